// Round 9
// baseline (102.561 us; speedup 1.0000x reference)
//
#include <hip/hip_runtime.h>
#include <math.h>

#define NN 64
#define DD 128
#define HH 256

typedef __attribute__((ext_vector_type(8))) short short8;
typedef __attribute__((ext_vector_type(4))) float f32x4;

// ws layout (floats):
//   P    [64][256] @ 0        (x @ cdW1[0:128]   + cdb1)
//   Q    [64][256] @ 16384    (x @ cdW1[128:256])
//   A    [64][256] @ 32768    (x @ cfW1[0:128]   + cfb1)
//   B    [64][256] @ 49152    (x @ cfW1[128:256])
//   C4   [64 d4][64 k]float4 @ 65536  (x @ cfW1[256:384], transposed)
//   W2T  bf16 [128 c][256 t] @ 81920  (cdW2 transposed, bf16)  (64 KB)

__device__ __forceinline__ short f2bf(float f) {
    unsigned u = __float_as_uint(f);
    unsigned r = (u + 0x7fffu + ((u >> 16) & 1u)) >> 16;
    return (short)r;
}

// Kernel A, 512 thr, grid 328. Blocks 0..319: projection p=bid>>6, node n=bid&63.
// Blocks 320..327: cdW2 -> W2T bf16 transpose, one latency round.
__global__ __launch_bounds__(512) void k_stage(
    const float* __restrict__ x, const int* __restrict__ inode,
    const float* __restrict__ cdW1, const float* __restrict__ cdb1,
    const float* __restrict__ cdW2,
    const float* __restrict__ cfW1, const float* __restrict__ cfb1,
    float* __restrict__ ws, float* __restrict__ out3)
{
    const int bid = blockIdx.x;
    const int tid = threadIdx.x;
    if (bid < 320) {
        __shared__ float xs[DD];
        __shared__ float4 red[8][64];
        const int p = bid >> 6;
        const int n = bid & 63;
        if (tid < DD) xs[tid] = x[n * DD + tid];
        __syncthreads();
        const int c4 = tid & 63;   // float4 column group
        const int dg = tid >> 6;   // 0..7, 16 d's each
        const float* Wp = (p == 0) ? cdW1
                        : (p == 1) ? (cdW1 + DD * HH)
                                   : (cfW1 + (p - 2) * DD * HH);
        const float4* Wp4 = (const float4*)Wp;
        float4 w[16];
#pragma unroll
        for (int q = 0; q < 16; ++q) w[q] = Wp4[(dg * 16 + q) * 64 + c4];
        float4 acc = {0.f, 0.f, 0.f, 0.f};
#pragma unroll
        for (int q = 0; q < 16; ++q) {
            const float xv = xs[dg * 16 + q];
            acc.x += xv * w[q].x; acc.y += xv * w[q].y;
            acc.z += xv * w[q].z; acc.w += xv * w[q].w;
        }
        red[dg][c4] = acc;
        __syncthreads();
        if (tid < 64) {
            float4 s = {0.f, 0.f, 0.f, 0.f};
#pragma unroll
            for (int g = 0; g < 8; ++g) {
                const float4 r = red[g][tid];
                s.x += r.x; s.y += r.y; s.z += r.z; s.w += r.w;
            }
            if (p == 0) {
                const float4 b = ((const float4*)cdb1)[tid];
                s.x += b.x; s.y += b.y; s.z += b.z; s.w += b.w;
                ((float4*)(ws))[n * 64 + tid] = s;
            } else if (p == 1) {
                ((float4*)(ws + 16384))[n * 64 + tid] = s;
            } else if (p == 2) {
                const float4 b = ((const float4*)cfb1)[tid];
                s.x += b.x; s.y += b.y; s.z += b.z; s.w += b.w;
                ((float4*)(ws + 32768))[n * 64 + tid] = s;
            } else if (p == 3) {
                ((float4*)(ws + 49152))[n * 64 + tid] = s;
            } else {
                ((float4*)(ws + 65536))[tid * 64 + n] = s;  // C4[d4][n]
            }
        }
    } else {
        // W2T[c][t] = bf16(cdW2[t][c]); 16 c's per block, 32 threads per c
        unsigned short* W2T = (unsigned short*)(ws + 81920);
        const int c  = (bid - 320) * 16 + (tid >> 5);
        const int t0 = (tid & 31) * 8;
        float v[8];
#pragma unroll
        for (int e = 0; e < 8; ++e) v[e] = cdW2[(t0 + e) * 128 + c];
        unsigned short pk[8];
#pragma unroll
        for (int e = 0; e < 8; ++e) pk[e] = (unsigned short)f2bf(v[e]);
        *(ulong2*)(W2T + c * HH + t0) = *(ulong2*)pk;
    }
}

// Kernel B, 256 thr, grid 515.  (idempotent: reads inputs+ws, writes outputs only)
__global__ __launch_bounds__(256) void k_main(
    const float* __restrict__ ws, const float* __restrict__ x,
    const int* __restrict__ inode, const float* __restrict__ ival,
    const float* __restrict__ cdb2, const float* __restrict__ cdW3,
    const float* __restrict__ cdb3,
    const float* __restrict__ cfW2, const float* __restrict__ cfb2,
    const float* __restrict__ ipW1, const float* __restrict__ ipb1,
    const float* __restrict__ ipW2, const float* __restrict__ ipb2,
    float* __restrict__ causal, float* __restrict__ conf,
    float* __restrict__ out3)
{
    const int bid = blockIdx.x;
    const int tid = threadIdx.x;
    if (bid < 256) {
        // ---- causal pairs via bf16 MFMA, no LDS main loop
        const int i  = bid >> 2;
        const int j0 = (bid & 3) * 16;
        const int wid  = tid >> 6;
        const int lane = tid & 63;
        const int lo = lane & 15;
        const int hi = lane >> 4;
        const int n0 = wid * 32;

        const float* Prow = ws + i * HH;
        const float* Qrow = ws + 16384 + (j0 + lo) * HH;
        const unsigned short* W2T = (const unsigned short*)(ws + 81920);

        f32x4 acc0 = {0.f, 0.f, 0.f, 0.f};
        f32x4 acc1 = {0.f, 0.f, 0.f, 0.f};
#pragma unroll
        for (int step = 0; step < 8; ++step) {
            const int kb = step * 32 + hi * 8;
            const float4 pa = *(const float4*)(Prow + kb);
            const float4 pb = *(const float4*)(Prow + kb + 4);
            const float4 qa = *(const float4*)(Qrow + kb);
            const float4 qb = *(const float4*)(Qrow + kb + 4);
            short8 af;
            af[0] = f2bf(fmaxf(pa.x + qa.x, 0.f));
            af[1] = f2bf(fmaxf(pa.y + qa.y, 0.f));
            af[2] = f2bf(fmaxf(pa.z + qa.z, 0.f));
            af[3] = f2bf(fmaxf(pa.w + qa.w, 0.f));
            af[4] = f2bf(fmaxf(pb.x + qb.x, 0.f));
            af[5] = f2bf(fmaxf(pb.y + qb.y, 0.f));
            af[6] = f2bf(fmaxf(pb.z + qb.z, 0.f));
            af[7] = f2bf(fmaxf(pb.w + qb.w, 0.f));
            const short8 b0 = *(const short8*)(W2T + (n0 + lo) * HH + kb);
            const short8 b1 = *(const short8*)(W2T + (n0 + 16 + lo) * HH + kb);
            acc0 = __builtin_amdgcn_mfma_f32_16x16x32_bf16(af, b0, acc0, 0, 0, 0);
            acc1 = __builtin_amdgcn_mfma_f32_16x16x32_bf16(af, b1, acc1, 0, 0, 0);
        }
        const int c0 = n0 + lo;
        const int c1 = n0 + 16 + lo;
        const float b2a = cdb2[c0], b2b = cdb2[c1];
        const float w3a = cdW3[c0], w3b = cdW3[c1];
        float pr[4];
#pragma unroll
        for (int r = 0; r < 4; ++r) {
            pr[r] = fmaxf(acc0[r] + b2a, 0.f) * w3a
                  + fmaxf(acc1[r] + b2b, 0.f) * w3b;
        }
#pragma unroll
        for (int m = 1; m <= 8; m <<= 1) {
#pragma unroll
            for (int r = 0; r < 4; ++r) pr[r] += __shfl_xor(pr[r], m, 64);
        }
        __shared__ float zp[4][16];
        if (lo == 0) {
#pragma unroll
            for (int r = 0; r < 4; ++r) zp[wid][hi * 4 + r] = pr[r];
        }
        __syncthreads();
        if (tid < 16) {
            const float z = zp[0][tid] + zp[1][tid] + zp[2][tid] + zp[3][tid] + cdb3[0];
            const float sg = 1.f / (1.f + expf(-z));
            const int j = j0 + tid;
            causal[i * NN + j] = (i == j) ? 0.f : sg;
        }
    } else if (bid < 512) {
        // ---- confounder triples
        const int u = bid - 256;
        const float* A  = ws + 32768;
        const float* B  = ws + 49152;
        const float* C4 = ws + 65536;
        __shared__ float smem[4352];
        float* s_s = smem;
        float* w2s = smem + 4096;
        const int i  = u >> 2;
        const int j0 = (u & 3) * 16;
        for (int v = tid; v < 16 * HH; v += 256) {
            const int jj = v >> 8, d = v & 255;
            s_s[v] = A[i * HH + d] + B[(j0 + jj) * HH + d];
        }
        if (tid < 64) ((float4*)w2s)[tid] = ((const float4*)cfW2)[tid];
        __syncthreads();

        const int k   = tid & 63;
        const int jj2 = tid >> 6;
        float acc[4] = {0.f, 0.f, 0.f, 0.f};
        const float4* C4v = (const float4*)C4;
        const float4* sv  = (const float4*)s_s;
        const float4* wv  = (const float4*)w2s;
        for (int ch = 0; ch < 8; ++ch) {
            float4 cr[8], wr[8];
#pragma unroll
            for (int q = 0; q < 8; ++q) {
                cr[q] = C4v[(ch * 8 + q) * 64 + k];
                wr[q] = wv[ch * 8 + q];
            }
#pragma unroll
            for (int p = 0; p < 4; ++p) {
                const int jj = p * 4 + jj2;
                float a = acc[p];
#pragma unroll
                for (int q = 0; q < 8; ++q) {
                    const float4 s4 = sv[jj * 64 + ch * 8 + q];
                    a += fmaxf(s4.x + cr[q].x, 0.f) * wr[q].x;
                    a += fmaxf(s4.y + cr[q].y, 0.f) * wr[q].y;
                    a += fmaxf(s4.z + cr[q].z, 0.f) * wr[q].z;
                    a += fmaxf(s4.w + cr[q].w, 0.f) * wr[q].w;
                }
                acc[p] = a;
            }
        }
        const float b2 = cfb2[0];
#pragma unroll
        for (int p = 0; p < 4; ++p) {
            const int j = j0 + p * 4 + jj2;
            const float z = acc[p] + b2;
            const float sg = 1.f / (1.f + expf(-z));
            const bool distinct = (i != j) && (j != k) && (i != k);
            conf[(i * NN + j) * NN + k] = distinct ? sg : 0.f;
        }
    } else if (bid == 512) {
        // ---- intervention MLP, d-parallel coalesced loads
        __shared__ float in_s[DD + 1];
        __shared__ float4 red[8][64];
        __shared__ float h_s[HH];
        const int node = inode[0];
        if (tid < DD) in_s[tid] = x[node * DD + tid];
        if (tid == DD) in_s[DD] = ival[0];
        __syncthreads();
        {
            const int c4 = tid & 63;
            const int dg = tid >> 6;
            const float4* W1v = (const float4*)ipW1;
            float4 acc = {0.f, 0.f, 0.f, 0.f};
#pragma unroll 8
            for (int r = 0; r < 32; ++r) {
                const int d = dg * 32 + r;
                const float xv = in_s[d];
                const float4 w = W1v[d * 64 + c4];
                acc.x += xv * w.x; acc.y += xv * w.y;
                acc.z += xv * w.z; acc.w += xv * w.w;
            }
            if (dg == 0) {
                const float xv = in_s[128];
                const float4 w = W1v[128 * 64 + c4];
                acc.x += xv * w.x; acc.y += xv * w.y;
                acc.z += xv * w.z; acc.w += xv * w.w;
            }
            red[dg][c4] = acc;
        }
        __syncthreads();
        if (tid < 64) {
            const float4 r0 = red[0][tid], r1 = red[1][tid];
            const float4 r2 = red[2][tid], r3 = red[3][tid];
            const float4 b = ((const float4*)ipb1)[tid];
            float4 h;
            h.x = fmaxf(r0.x + r1.x + r2.x + r3.x + b.x, 0.f);
            h.y = fmaxf(r0.y + r1.y + r2.y + r3.y + b.y, 0.f);
            h.z = fmaxf(r0.z + r1.z + r2.z + r3.z + b.z, 0.f);
            h.w = fmaxf(r0.w + r1.w + r2.w + r3.w + b.w, 0.f);
            ((float4*)h_s)[tid] = h;
        }
        __syncthreads();
        {
            const int c4 = tid & 31;
            const int ug = tid >> 5;
            const float4* W2v = (const float4*)ipW2;
            float4 acc = {0.f, 0.f, 0.f, 0.f};
#pragma unroll 8
            for (int r = 0; r < 32; ++r) {
                const int uu = ug * 32 + r;
                const float hv = h_s[uu];
                const float4 w = W2v[uu * 32 + c4];
                acc.x += hv * w.x; acc.y += hv * w.y;
                acc.z += hv * w.z; acc.w += hv * w.w;
            }
            ((float4*)red)[ug * 32 + c4] = acc;
        }
        __syncthreads();
        if (tid < 32) {
            float4 s = ((const float4*)ipb2)[tid];
#pragma unroll
            for (int g = 0; g < 8; ++g) {
                const float4 r = ((const float4*)red)[g * 32 + tid];
                s.x += r.x; s.y += r.y; s.z += r.z; s.w += r.w;
            }
            ((float4*)(out3 + node * DD))[tid] = s;
        }
    } else {
        // ---- out3 copy (rows != node), 2 blocks x 32 rows
        const int node = inode[0];
        const int n = (bid - 513) * 32 + (tid >> 3);
        const int part = tid & 7;
        if (n != node) {
            const float4* src = (const float4*)(x + n * DD);
            float4* dst = (float4*)(out3 + n * DD);
#pragma unroll
            for (int e = 0; e < 4; ++e) dst[part * 4 + e] = src[part * 4 + e];
        }
    }
}

extern "C" void kernel_launch(void* const* d_in, const int* in_sizes, int n_in,
                              void* d_out, int out_size, void* d_ws, size_t ws_size,
                              hipStream_t stream) {
    const float* x    = (const float*)d_in[0];
    const int*   node = (const int*)d_in[1];
    const float* ival = (const float*)d_in[2];
    const float* cdW1 = (const float*)d_in[3];
    const float* cdb1 = (const float*)d_in[4];
    const float* cdW2 = (const float*)d_in[5];
    const float* cdb2 = (const float*)d_in[6];
    const float* cdW3 = (const float*)d_in[7];
    const float* cdb3 = (const float*)d_in[8];
    const float* cfW1 = (const float*)d_in[9];
    const float* cfb1 = (const float*)d_in[10];
    const float* cfW2 = (const float*)d_in[11];
    const float* cfb2 = (const float*)d_in[12];
    const float* ipW1 = (const float*)d_in[13];
    const float* ipb1 = (const float*)d_in[14];
    const float* ipW2 = (const float*)d_in[15];
    const float* ipb2 = (const float*)d_in[16];

    float* out    = (float*)d_out;
    float* causal = out;                           // 4096
    float* conf   = out + NN * NN;                 // 262144
    float* out3   = out + NN * NN + NN * NN * NN;  // 8192
    float* wsf    = (float*)d_ws;

    k_stage<<<dim3(328), dim3(512), 0, stream>>>(
        x, node, cdW1, cdb1, cdW2, cfW1, cfb1, wsf, out3);
    // MEASUREMENT: k_main is idempotent (pure function of inputs+ws).
    // 5 launches => dur_us = k_stage + 5*k_main + 6*L;
    // with R8 baseline (1x k_main) = 32.4:  k_main + L = (dur - 32.4)/4.
    for (int rep = 0; rep < 5; ++rep) {
        k_main<<<dim3(515), dim3(256), 0, stream>>>(
            wsf, x, node, ival, cdb2, cdW3, cdb3, cfW2, cfb2,
            ipW1, ipb1, ipW2, ipb2, causal, conf, out3);
    }
}

// Round 10
// 31.280 us; speedup vs baseline: 3.2788x; 3.2788x over previous
//
#include <hip/hip_runtime.h>
#include <math.h>

#define NN 64
#define DD 128
#define HH 256

typedef __attribute__((ext_vector_type(8))) short short8;
typedef __attribute__((ext_vector_type(4))) float f32x4;

// ws layout (floats):
//   P    [64][256] @ 0        (x @ cdW1[0:128]   + cdb1)
//   Q    [64][256] @ 16384    (x @ cdW1[128:256])
//   A    [64][256] @ 32768    (x @ cfW1[0:128]   + cfb1)
//   B    [64][256] @ 49152    (x @ cfW1[128:256])
//   C4   [64 d4][64 k]float4 @ 65536  (x @ cfW1[256:384], transposed)
//   W2T  bf16 [128 c][256 t] @ 81920  (cdW2 transposed, bf16)  (64 KB)

__device__ __forceinline__ short f2bf(float f) {
    unsigned u = __float_as_uint(f);
    unsigned r = (u + 0x7fffu + ((u >> 16) & 1u)) >> 16;
    return (short)r;
}

// Kernel A, 512 thr, grid 328. Blocks 0..319: projection p=bid>>6, node n=bid&63.
// Blocks 320..327: cdW2 -> W2T bf16 transpose, one latency round.
__global__ __launch_bounds__(512) void k_stage(
    const float* __restrict__ x, const int* __restrict__ inode,
    const float* __restrict__ cdW1, const float* __restrict__ cdb1,
    const float* __restrict__ cdW2,
    const float* __restrict__ cfW1, const float* __restrict__ cfb1,
    float* __restrict__ ws, float* __restrict__ out3)
{
    const int bid = blockIdx.x;
    const int tid = threadIdx.x;
    if (bid < 320) {
        __shared__ float xs[DD];
        __shared__ float4 red[8][64];
        const int p = bid >> 6;
        const int n = bid & 63;
        if (tid < DD) xs[tid] = x[n * DD + tid];
        __syncthreads();
        const int c4 = tid & 63;   // float4 column group
        const int dg = tid >> 6;   // 0..7, 16 d's each
        const float* Wp = (p == 0) ? cdW1
                        : (p == 1) ? (cdW1 + DD * HH)
                                   : (cfW1 + (p - 2) * DD * HH);
        const float4* Wp4 = (const float4*)Wp;
        float4 w[16];
#pragma unroll
        for (int q = 0; q < 16; ++q) w[q] = Wp4[(dg * 16 + q) * 64 + c4];
        float4 acc = {0.f, 0.f, 0.f, 0.f};
#pragma unroll
        for (int q = 0; q < 16; ++q) {
            const float xv = xs[dg * 16 + q];
            acc.x += xv * w[q].x; acc.y += xv * w[q].y;
            acc.z += xv * w[q].z; acc.w += xv * w[q].w;
        }
        red[dg][c4] = acc;
        __syncthreads();
        if (tid < 64) {
            float4 s = {0.f, 0.f, 0.f, 0.f};
#pragma unroll
            for (int g = 0; g < 8; ++g) {
                const float4 r = red[g][tid];
                s.x += r.x; s.y += r.y; s.z += r.z; s.w += r.w;
            }
            if (p == 0) {
                const float4 b = ((const float4*)cdb1)[tid];
                s.x += b.x; s.y += b.y; s.z += b.z; s.w += b.w;
                ((float4*)(ws))[n * 64 + tid] = s;
            } else if (p == 1) {
                ((float4*)(ws + 16384))[n * 64 + tid] = s;
            } else if (p == 2) {
                const float4 b = ((const float4*)cfb1)[tid];
                s.x += b.x; s.y += b.y; s.z += b.z; s.w += b.w;
                ((float4*)(ws + 32768))[n * 64 + tid] = s;
            } else if (p == 3) {
                ((float4*)(ws + 49152))[n * 64 + tid] = s;
            } else {
                ((float4*)(ws + 65536))[tid * 64 + n] = s;  // C4[d4][n]
            }
        }
    } else {
        // W2T[c][t] = bf16(cdW2[t][c]); 16 c's per block, 32 threads per c
        unsigned short* W2T = (unsigned short*)(ws + 81920);
        const int c  = (bid - 320) * 16 + (tid >> 5);
        const int t0 = (tid & 31) * 8;
        float v[8];
#pragma unroll
        for (int e = 0; e < 8; ++e) v[e] = cdW2[(t0 + e) * 128 + c];
        unsigned short pk[8];
#pragma unroll
        for (int e = 0; e < 8; ++e) pk[e] = (unsigned short)f2bf(v[e]);
        *(ulong2*)(W2T + c * HH + t0) = *(ulong2*)pk;
    }
}

// Kernel B, 256 thr, grid 515.
//   bid <  256: pairs MFMA unit (i=bid>>2, j0=(bid&3)*16)
//   bid <  512: triple unit — ZERO-LDS version (A/B/w broadcast from L1, s=A+B in VALU)
//   bid == 512: intervention MLP
//   bid 513/514: out3 row copies
__global__ __launch_bounds__(256) void k_main(
    const float* __restrict__ ws, const float* __restrict__ x,
    const int* __restrict__ inode, const float* __restrict__ ival,
    const float* __restrict__ cdb2, const float* __restrict__ cdW3,
    const float* __restrict__ cdb3,
    const float* __restrict__ cfW2, const float* __restrict__ cfb2,
    const float* __restrict__ ipW1, const float* __restrict__ ipb1,
    const float* __restrict__ ipW2, const float* __restrict__ ipb2,
    float* __restrict__ causal, float* __restrict__ conf,
    float* __restrict__ out3)
{
    const int bid = blockIdx.x;
    const int tid = threadIdx.x;
    if (bid < 256) {
        // ---- causal pairs via bf16 MFMA, no LDS main loop
        const int i  = bid >> 2;
        const int j0 = (bid & 3) * 16;
        const int wid  = tid >> 6;
        const int lane = tid & 63;
        const int lo = lane & 15;
        const int hi = lane >> 4;
        const int n0 = wid * 32;

        const float* Prow = ws + i * HH;
        const float* Qrow = ws + 16384 + (j0 + lo) * HH;
        const unsigned short* W2T = (const unsigned short*)(ws + 81920);

        f32x4 acc0 = {0.f, 0.f, 0.f, 0.f};
        f32x4 acc1 = {0.f, 0.f, 0.f, 0.f};
#pragma unroll
        for (int step = 0; step < 8; ++step) {
            const int kb = step * 32 + hi * 8;
            const float4 pa = *(const float4*)(Prow + kb);
            const float4 pb = *(const float4*)(Prow + kb + 4);
            const float4 qa = *(const float4*)(Qrow + kb);
            const float4 qb = *(const float4*)(Qrow + kb + 4);
            short8 af;
            af[0] = f2bf(fmaxf(pa.x + qa.x, 0.f));
            af[1] = f2bf(fmaxf(pa.y + qa.y, 0.f));
            af[2] = f2bf(fmaxf(pa.z + qa.z, 0.f));
            af[3] = f2bf(fmaxf(pa.w + qa.w, 0.f));
            af[4] = f2bf(fmaxf(pb.x + qb.x, 0.f));
            af[5] = f2bf(fmaxf(pb.y + qb.y, 0.f));
            af[6] = f2bf(fmaxf(pb.z + qb.z, 0.f));
            af[7] = f2bf(fmaxf(pb.w + qb.w, 0.f));
            const short8 b0 = *(const short8*)(W2T + (n0 + lo) * HH + kb);
            const short8 b1 = *(const short8*)(W2T + (n0 + 16 + lo) * HH + kb);
            acc0 = __builtin_amdgcn_mfma_f32_16x16x32_bf16(af, b0, acc0, 0, 0, 0);
            acc1 = __builtin_amdgcn_mfma_f32_16x16x32_bf16(af, b1, acc1, 0, 0, 0);
        }
        const int c0 = n0 + lo;
        const int c1 = n0 + 16 + lo;
        const float b2a = cdb2[c0], b2b = cdb2[c1];
        const float w3a = cdW3[c0], w3b = cdW3[c1];
        float pr[4];
#pragma unroll
        for (int r = 0; r < 4; ++r) {
            pr[r] = fmaxf(acc0[r] + b2a, 0.f) * w3a
                  + fmaxf(acc1[r] + b2b, 0.f) * w3b;
        }
#pragma unroll
        for (int m = 1; m <= 8; m <<= 1) {
#pragma unroll
            for (int r = 0; r < 4; ++r) pr[r] += __shfl_xor(pr[r], m, 64);
        }
        __shared__ float zp[4][16];
        if (lo == 0) {
#pragma unroll
            for (int r = 0; r < 4; ++r) zp[wid][hi * 4 + r] = pr[r];
        }
        __syncthreads();
        if (tid < 16) {
            const float z = zp[0][tid] + zp[1][tid] + zp[2][tid] + zp[3][tid] + cdb3[0];
            const float sg = 1.f / (1.f + expf(-z));
            const int j = j0 + tid;
            causal[i * NN + j] = (i == j) ? 0.f : sg;
        }
    } else if (bid < 512) {
        // ---- confounder triples, zero-LDS: all operands via registers/L1
        const int u = bid - 256;
        const float* A  = ws + 32768;
        const float* B  = ws + 49152;
        const float* C4 = ws + 65536;
        const int i  = u >> 2;
        const int j0 = (u & 3) * 16;
        const int k   = tid & 63;
        const int jj2 = tid >> 6;
        const float4* C4v = (const float4*)C4;
        const float4* Av  = (const float4*)(A + i * HH);
        const float4* wv  = (const float4*)cfW2;
        float acc[4] = {0.f, 0.f, 0.f, 0.f};
        for (int ch = 0; ch < 8; ++ch) {
            float4 cr[8], av[8], wr[8];
#pragma unroll
            for (int q = 0; q < 8; ++q) {
                cr[q] = C4v[(ch * 8 + q) * 64 + k];   // coalesced over k-lanes
                av[q] = Av[ch * 8 + q];               // wave-uniform broadcast (L1)
                wr[q] = wv[ch * 8 + q];               // wave-uniform broadcast (L1)
            }
#pragma unroll
            for (int p = 0; p < 4; ++p) {
                const int j = j0 + p * 4 + jj2;
                const float4* Bv = (const float4*)(B + j * HH);
                float4 bv[8];
#pragma unroll
                for (int q = 0; q < 8; ++q) bv[q] = Bv[ch * 8 + q];  // broadcast
                float a = acc[p];
#pragma unroll
                for (int q = 0; q < 8; ++q) {
                    // s = A + B (same assoc order as LDS version), then + c
                    const float sx = av[q].x + bv[q].x;
                    const float sy = av[q].y + bv[q].y;
                    const float sz = av[q].z + bv[q].z;
                    const float sw = av[q].w + bv[q].w;
                    a += fmaxf(sx + cr[q].x, 0.f) * wr[q].x;
                    a += fmaxf(sy + cr[q].y, 0.f) * wr[q].y;
                    a += fmaxf(sz + cr[q].z, 0.f) * wr[q].z;
                    a += fmaxf(sw + cr[q].w, 0.f) * wr[q].w;
                }
                acc[p] = a;
            }
        }
        const float b2 = cfb2[0];
#pragma unroll
        for (int p = 0; p < 4; ++p) {
            const int j = j0 + p * 4 + jj2;
            const float z = acc[p] + b2;
            const float sg = 1.f / (1.f + expf(-z));
            const bool distinct = (i != j) && (j != k) && (i != k);
            conf[(i * NN + j) * NN + k] = distinct ? sg : 0.f;
        }
    } else if (bid == 512) {
        // ---- intervention MLP, d-parallel coalesced loads
        __shared__ float in_s[DD + 1];
        __shared__ float4 red[8][64];
        __shared__ float h_s[HH];
        const int node = inode[0];
        if (tid < DD) in_s[tid] = x[node * DD + tid];
        if (tid == DD) in_s[DD] = ival[0];
        __syncthreads();
        {
            const int c4 = tid & 63;
            const int dg = tid >> 6;
            const float4* W1v = (const float4*)ipW1;
            float4 acc = {0.f, 0.f, 0.f, 0.f};
#pragma unroll 8
            for (int r = 0; r < 32; ++r) {
                const int d = dg * 32 + r;
                const float xv = in_s[d];
                const float4 w = W1v[d * 64 + c4];
                acc.x += xv * w.x; acc.y += xv * w.y;
                acc.z += xv * w.z; acc.w += xv * w.w;
            }
            if (dg == 0) {
                const float xv = in_s[128];
                const float4 w = W1v[128 * 64 + c4];
                acc.x += xv * w.x; acc.y += xv * w.y;
                acc.z += xv * w.z; acc.w += xv * w.w;
            }
            red[dg][c4] = acc;
        }
        __syncthreads();
        if (tid < 64) {
            const float4 r0 = red[0][tid], r1 = red[1][tid];
            const float4 r2 = red[2][tid], r3 = red[3][tid];
            const float4 b = ((const float4*)ipb1)[tid];
            float4 h;
            h.x = fmaxf(r0.x + r1.x + r2.x + r3.x + b.x, 0.f);
            h.y = fmaxf(r0.y + r1.y + r2.y + r3.y + b.y, 0.f);
            h.z = fmaxf(r0.z + r1.z + r2.z + r3.z + b.z, 0.f);
            h.w = fmaxf(r0.w + r1.w + r2.w + r3.w + b.w, 0.f);
            ((float4*)h_s)[tid] = h;
        }
        __syncthreads();
        {
            const int c4 = tid & 31;
            const int ug = tid >> 5;
            const float4* W2v = (const float4*)ipW2;
            float4 acc = {0.f, 0.f, 0.f, 0.f};
#pragma unroll 8
            for (int r = 0; r < 32; ++r) {
                const int uu = ug * 32 + r;
                const float hv = h_s[uu];
                const float4 w = W2v[uu * 32 + c4];
                acc.x += hv * w.x; acc.y += hv * w.y;
                acc.z += hv * w.z; acc.w += hv * w.w;
            }
            ((float4*)red)[ug * 32 + c4] = acc;
        }
        __syncthreads();
        if (tid < 32) {
            float4 s = ((const float4*)ipb2)[tid];
#pragma unroll
            for (int g = 0; g < 8; ++g) {
                const float4 r = ((const float4*)red)[g * 32 + tid];
                s.x += r.x; s.y += r.y; s.z += r.z; s.w += r.w;
            }
            ((float4*)(out3 + node * DD))[tid] = s;
        }
    } else {
        // ---- out3 copy (rows != node), 2 blocks x 32 rows
        const int node = inode[0];
        const int n = (bid - 513) * 32 + (tid >> 3);
        const int part = tid & 7;
        if (n != node) {
            const float4* src = (const float4*)(x + n * DD);
            float4* dst = (float4*)(out3 + n * DD);
#pragma unroll
            for (int e = 0; e < 4; ++e) dst[part * 4 + e] = src[part * 4 + e];
        }
    }
}

extern "C" void kernel_launch(void* const* d_in, const int* in_sizes, int n_in,
                              void* d_out, int out_size, void* d_ws, size_t ws_size,
                              hipStream_t stream) {
    const float* x    = (const float*)d_in[0];
    const int*   node = (const int*)d_in[1];
    const float* ival = (const float*)d_in[2];
    const float* cdW1 = (const float*)d_in[3];
    const float* cdb1 = (const float*)d_in[4];
    const float* cdW2 = (const float*)d_in[5];
    const float* cdb2 = (const float*)d_in[6];
    const float* cdW3 = (const float*)d_in[7];
    const float* cdb3 = (const float*)d_in[8];
    const float* cfW1 = (const float*)d_in[9];
    const float* cfb1 = (const float*)d_in[10];
    const float* cfW2 = (const float*)d_in[11];
    const float* cfb2 = (const float*)d_in[12];
    const float* ipW1 = (const float*)d_in[13];
    const float* ipb1 = (const float*)d_in[14];
    const float* ipW2 = (const float*)d_in[15];
    const float* ipb2 = (const float*)d_in[16];

    float* out    = (float*)d_out;
    float* causal = out;                           // 4096
    float* conf   = out + NN * NN;                 // 262144
    float* out3   = out + NN * NN + NN * NN * NN;  // 8192
    float* wsf    = (float*)d_ws;

    k_stage<<<dim3(328), dim3(512), 0, stream>>>(
        x, node, cdW1, cdb1, cdW2, cfW1, cfb1, wsf, out3);
    k_main<<<dim3(515), dim3(256), 0, stream>>>(
        wsf, x, node, ival, cdb2, cdW3, cdb3, cfW2, cfb2,
        ipW1, ipb1, ipW2, ipb2, causal, conf, out3);
}